// Round 5
// baseline (149.633 us; speedup 1.0000x reference)
//
#include <hip/hip_runtime.h>

// GraphConvolution: out = relu(D^-1/2 (2I - adj) D^-1/2 (input@weight) + b)
// N=8192, F_in=512, F_out=256. fp16 MFMA internally (needs 2^-12 rounding).
//
// R5: k3's B operand (sT, L2-resident, zero intra-CU reuse) moves LDS->VGPR:
// inline-asm global loads with hand-counted vmcnt; wave tile 64Mx32N so B is
// loaded exactly once per block. LDS carries only the A tile (72 KB/step vs
// 136 KB in R4 -> LDS no longer contends with the HBM adj stream).

typedef _Float16 h4 __attribute__((ext_vector_type(4)));
typedef _Float16 h8 __attribute__((ext_vector_type(8)));
typedef float f4 __attribute__((ext_vector_type(4)));

__device__ __forceinline__ void gload_lds16(const void* g, void* l) {
    __builtin_amdgcn_global_load_lds(
        (const __attribute__((address_space(1))) void*)g,
        (__attribute__((address_space(3))) void*)l, 16, 0, 0);
}

// two 16B loads via inline asm: compiler cannot attach its own vmcnt(0)
__device__ __forceinline__ void gload2(const float* p, f4& x, f4& y) {
    asm volatile("global_load_dwordx4 %0, %2, off\n\t"
                 "global_load_dwordx4 %1, %2, off offset:16"
                 : "=&v"(x), "=&v"(y)
                 : "v"(p)
                 : "memory");
}
// B fragment pair (kk=0 at +0, kk=1 at +64B) from linear sT
__device__ __forceinline__ void gloadB2(const char* p, h8& x, h8& y) {
    asm volatile("global_load_dwordx4 %0, %2, off\n\t"
                 "global_load_dwordx4 %1, %2, off offset:64"
                 : "=&v"(x), "=&v"(y)
                 : "v"(p)
                 : "memory");
}

// ---------------------------------------------------------------------------
// k0: weight [512][256] f32 -> W^T [256 j][512 k] fp16, XOR-swizzled within
// each 128B k-chunk: byte ^= ((j&7)<<4)  (consumed by k2's gload_lds path).
__global__ __launch_bounds__(256) void k0_wt(const float* __restrict__ weight,
                                             char* __restrict__ wt) {
    const int idx = blockIdx.x * 256 + threadIdx.x;   // 131072 total
    const int k = idx >> 8, j = idx & 255;
    const _Float16 h = (_Float16)weight[idx];
    const int off = j * 1024 + ((k >> 6) << 7) + (((k & 63) << 1) ^ ((j & 7) << 4));
    *(_Float16*)(wt + off) = h;
}

// ---------------------------------------------------------------------------
// k1: dinv[r] = 1/sqrt(2 + sum_k adj[r][k])
__global__ __launch_bounds__(256) void k1_deg(const float* __restrict__ adj,
                                              float* __restrict__ dinv) {
    const int r = blockIdx.x;
    const float4* rp = (const float4*)(adj + (size_t)r * 8192);
    const int t = threadIdx.x;
    float s = 0.f;
#pragma unroll
    for (int i = 0; i < 8; ++i) {
        float4 v = rp[t + i * 256];
        s += (v.x + v.y) + (v.z + v.w);
    }
#pragma unroll
    for (int off = 32; off > 0; off >>= 1) s += __shfl_down(s, off, 64);
    __shared__ float part[4];
    if ((t & 63) == 0) part[t >> 6] = s;
    __syncthreads();
    if (t == 0) {
        float deg = (part[0] + part[1]) + (part[2] + part[3]);
        dinv[r] = 1.0f / sqrtf(2.0f + deg);
    }
}

// ---------------------------------------------------------------------------
// k2: support = input @ weight; writes S'^T[j][k] = dinv[k]*support[k][j] as
// fp16, transposed, LINEAR (k3 loads it straight to VGPR). 256 blocks.
__global__ __launch_bounds__(512) void k2_support(const float* __restrict__ input,
                                                  const char* __restrict__ wt,
                                                  const float* __restrict__ dinv,
                                                  char* __restrict__ sT) {
    __shared__ char smem[4096 + 32768];   // A [32][128B] + B [256][128B]
    const int t = threadIdx.x, w = t >> 6, l = t & 63;
    const int r0 = (int)blockIdx.x * 32;
    const int arow = t >> 4, ak4 = t & 15;
    const int bj = l >> 3, bb = (l & 7) * 16;

    f4 acc[2][2] = {};

    for (int kt = 0; kt < 8; ++kt) {
        const int k0 = kt * 64;
        __syncthreads();
        // stage A: 32 rows x 64 k fp16, swizzled
        {
            float4 v = *(const float4*)(input + (size_t)(r0 + arow) * 512 + k0 + ak4 * 4);
            h4 h;
            h[0] = (_Float16)v.x; h[1] = (_Float16)v.y;
            h[2] = (_Float16)v.z; h[3] = (_Float16)v.w;
            *(h4*)(smem + arow * 128 + ((ak4 * 8) ^ ((arow & 7) << 4))) = h;
        }
        // stage B: W^T tile [256][64] fp16 via global_load_lds (pre-swizzled)
#pragma unroll
        for (int q = 0; q < 4; ++q) {
            const int c = q * 8 + w;
            gload_lds16(wt + (size_t)(c * 8 + bj) * 1024 + kt * 128 + bb,
                        smem + 4096 + c * 1024);
        }
        __syncthreads();
#pragma unroll
        for (int kk = 0; kk < 2; ++kk) {
            const int ko = kk * 64 + ((l >> 4) << 4);
            h8 a[2], b[2];
#pragma unroll
            for (int m = 0; m < 2; ++m) {
                const int r = m * 16 + (l & 15);
                a[m] = *(const h8*)(smem + r * 128 + (ko ^ ((r & 7) << 4)));
            }
#pragma unroll
            for (int n = 0; n < 2; ++n) {
                const int j = w * 32 + n * 16 + (l & 15);
                b[n] = *(const h8*)(smem + 4096 + j * 128 + (ko ^ ((j & 7) << 4)));
            }
#pragma unroll
            for (int m = 0; m < 2; ++m)
#pragma unroll
                for (int n = 0; n < 2; ++n)
                    acc[m][n] = __builtin_amdgcn_mfma_f32_16x16x32_f16(a[m], b[n], acc[m][n], 0, 0, 0);
        }
    }
    // S'^T[j][k] fp16, linear
#pragma unroll
    for (int m = 0; m < 2; ++m)
#pragma unroll
        for (int n = 0; n < 2; ++n) {
            const int j = w * 32 + n * 16 + (l & 15);
            const int k0r = r0 + m * 16 + ((l >> 4) << 2);
            h4 h;
#pragma unroll
            for (int r = 0; r < 4; ++r)
                h[r] = (_Float16)(dinv[k0r + r] * acc[m][n][r]);
            *(h4*)(sT + (size_t)j * 16384 + (size_t)k0r * 2) = h;
        }
}

// ---------------------------------------------------------------------------
// k3: partial[i][j] = sum_{k in split} (2I - adj)[i][k] * S'T[j][k]
// BM=64, BN=256, BK=64, 8 waves each computing 64Mx32N (full M, unique N ->
// B loaded exactly once per block). 512 blocks (2/CU). A double-buffered in
// LDS (2x8KB). All vm ops inline-asm, counted vmcnt, raw barriers.
__global__ __launch_bounds__(512, 4) void k3_spmm(const float* __restrict__ adj,
                                                  const char* __restrict__ sT,
                                                  float* __restrict__ part,
                                                  float* __restrict__ out,
                                                  int steps) {
    __shared__ __align__(16) char smem[2][8192];   // A tiles [64 rows][128 B]
    const int t = threadIdx.x;
    const int w = t >> 6, l = t & 63;
    const int i0 = (int)blockIdx.x * 64;
    const int ks0 = (int)blockIdx.y * steps * 64;
    const int dkt = (i0 - ks0) >> 6;   // uniform: K-step holding the diagonal

    const int arow = t >> 3;            // 0..63
    const int ak8 = (t & 7) * 8;        // 8 consecutive k per thread
    const int arow_g = i0 + arow;
    const float* aptr = adj + (size_t)arow_g * 8192 + ks0 + ak8;
    const int a_off = arow * 128 + (((t & 7) << 4) ^ ((arow & 7) << 4));

    // B pointers: wave w owns j in [w*32, w*32+32); n in {0,1} selects 16-j half.
    // lane: j += (l&15), k = (l>>4)*8; per step advance 128 B.
    const char* bp0 = sT + ((size_t)(w * 32 + (l & 15)) * 8192 + ks0 + ((l >> 4) << 3)) * 2;
    const char* bp1 = bp0 + (size_t)16 * 16384;

    f4 acc[4][2] = {};
    h8 bv[2][2];                        // [kk][n], single-buffered per step
    f4 ax0, ay0, ax1, ay1;              // adj ping-pong (depth-2)

    auto loadB = [&](int kt) {
        gloadB2(bp0 + (size_t)kt * 128, bv[0][0], bv[1][0]);
        gloadB2(bp1 + (size_t)kt * 128, bv[0][1], bv[1][1]);
    };
    auto waitB = [&]() {   // placed with the right vmcnt at each site via asm below
    };
    auto writeA = [&](char* buf, int kt, const f4 x, const f4 y) {
        const int kg = ks0 + kt * 64 + ak8;
        h8 h;
        if (kt == dkt) {
#pragma unroll
            for (int e = 0; e < 4; ++e)
                h[e] = (_Float16)((arow_g == kg + e) ? 2.0f - x[e] : -x[e]);
#pragma unroll
            for (int e = 0; e < 4; ++e)
                h[4 + e] = (_Float16)((arow_g == kg + 4 + e) ? 2.0f - y[e] : -y[e]);
        } else {
#pragma unroll
            for (int e = 0; e < 4; ++e) h[e] = (_Float16)(-x[e]);
#pragma unroll
            for (int e = 0; e < 4; ++e) h[4 + e] = (_Float16)(-y[e]);
        }
        *(h8*)(buf + a_off) = h;
    };
    auto compute = [&](const char* A) {
#pragma unroll
        for (int kk = 0; kk < 2; ++kk) {
            const int ko = kk * 64 + ((l >> 4) << 4);
            h8 a[4];
#pragma unroll
            for (int m = 0; m < 4; ++m) {
                const int r = m * 16 + (l & 15);
                a[m] = *(const h8*)(A + r * 128 + (ko ^ ((r & 7) << 4)));
            }
#pragma unroll
            for (int m = 0; m < 4; ++m)
#pragma unroll
                for (int n = 0; n < 2; ++n)
                    acc[m][n] = __builtin_amdgcn_mfma_f32_16x16x32_f16(a[m], bv[kk][n], acc[m][n], 0, 0, 0);
        }
    };

#define WAIT_ADJ(N, X, Y)                                                     \
    asm volatile("s_waitcnt vmcnt(" #N ")" : "+v"(X), "+v"(Y) :: "memory");   \
    __builtin_amdgcn_sched_barrier(0);
#define WAIT_B(N)                                                             \
    asm volatile("s_waitcnt vmcnt(" #N ")"                                    \
                 : "+v"(bv[0][0]), "+v"(bv[0][1]), "+v"(bv[1][0]), "+v"(bv[1][1]) \
                 :: "memory");                                                \
    __builtin_amdgcn_sched_barrier(0);
#define BARRIER()                                                             \
    asm volatile("s_waitcnt lgkmcnt(0)\n\ts_barrier" ::: "memory");           \
    __builtin_amdgcn_sched_barrier(0);

    // prologue: adj(0),adj(1) in flight; A(0)->LDS; barrier
    gload2(aptr, ax0, ay0);
    gload2(aptr + 64, ax1, ay1);
    WAIT_ADJ(2, ax0, ay0)
    writeA(smem[0], 0, ax0, ay0);
    BARRIER()

    // body(kt): loadB(kt)[4]; issue adj(kt+2)[2]; vmcnt(6)->adj(kt+1) ready;
    // writeA(kt+1); vmcnt(2)->B(kt) ready (adj(kt+2) stays in flight);
    // compute(kt); barrier.
#define BODY(kt, XC, YC, XN, YN, BUFC, BUFN)                                  \
    {                                                                         \
        loadB(kt);                                                            \
        gload2(aptr + (size_t)(kt + 2) * 64, XC, YC);                         \
        WAIT_ADJ(6, XN, YN)                                                   \
        writeA(BUFN, (kt) + 1, XN, YN);                                       \
        WAIT_B(2)                                                             \
        compute(BUFC);                                                        \
        BARRIER()                                                             \
    }

    for (int kt2 = 0; kt2 + 3 <= steps; kt2 += 2) {
        BODY(kt2,     ax0, ay0, ax1, ay1, smem[0], smem[1])
        BODY(kt2 + 1, ax1, ay1, ax0, ay0, smem[1], smem[0])
    }
    // peeled kt = steps-2 (even; consumes adj(steps-1) in ax1/ay1, no new adj)
    {
        loadB(steps - 2);
        WAIT_ADJ(4, ax1, ay1)
        writeA(smem[1], steps - 1, ax1, ay1);
        WAIT_B(0)
        compute(smem[0]);
        BARRIER()
    }
    // peeled kt = steps-1
    {
        loadB(steps - 1);
        WAIT_B(0)
        compute(smem[1]);
    }
#undef BODY
#undef WAIT_ADJ
#undef WAIT_B
#undef BARRIER

    // write f32 partial (last split writes into d_out)
    float* dst = (blockIdx.y == gridDim.y - 1) ? out
               : part + (size_t)blockIdx.y * (8192 * 256);
#pragma unroll
    for (int m = 0; m < 4; ++m)
#pragma unroll
        for (int n = 0; n < 2; ++n) {
            const int j = w * 32 + n * 16 + (l & 15);
            const int ib = i0 + m * 16 + ((l >> 4) << 2);
#pragma unroll
            for (int r = 0; r < 4; ++r)
                dst[(size_t)(ib + r) * 256 + j] = acc[m][n][r];
        }
}

// ---------------------------------------------------------------------------
// k4: out = relu(dinv[i] * (sum of partials) + b[j]); last partial is in out.
__global__ __launch_bounds__(256) void k4_fin(const float* __restrict__ part,
                                              float* __restrict__ out,
                                              const float* __restrict__ dinv,
                                              const float* __restrict__ bias,
                                              int nsplit) {
    const int idx = blockIdx.x * 256 + threadIdx.x;   // 524288 float4 groups
    float4 s = ((const float4*)out)[idx];
    for (int sp = 0; sp < nsplit - 1; ++sp)
        s += ((const float4*)(part + (size_t)sp * (8192 * 256)))[idx];
    const float dv = dinv[idx >> 6];
    const float4 b = ((const float4*)bias)[idx & 63];
    float4 r;
    r.x = fmaxf(dv * s.x + b.x, 0.f);
    r.y = fmaxf(dv * s.y + b.y, 0.f);
    r.z = fmaxf(dv * s.z + b.z, 0.f);
    r.w = fmaxf(dv * s.w + b.w, 0.f);
    ((float4*)out)[idx] = r;
}

// ---------------------------------------------------------------------------
extern "C" void kernel_launch(void* const* d_in, const int* in_sizes, int n_in,
                              void* d_out, int out_size, void* d_ws, size_t ws_size,
                              hipStream_t stream) {
    const float* input  = (const float*)d_in[0];   // [8192][512]
    const float* adj    = (const float*)d_in[1];   // [8192][8192]
    const float* weight = (const float*)d_in[2];   // [512][256]
    const float* bias   = (const float*)d_in[3];   // [256]
    float* out = (float*)d_out;                    // [8192][256]

    char* ws = (char*)d_ws;
    float* dinv = (float*)ws;                         // 32 KB
    char*  wt   = ws + 32768;                         // 256 KB
    char*  sT   = ws + 294912;                        // 4 MB (fp16, linear)
    float* part = (float*)(ws + 294912 + 4194304);    // (nsplit-1) * 8 MB

    const size_t base = 294912 + 4194304;
    int nsplit = 1;
    if (ws_size >= base + 3 * 8388608) nsplit = 4;        // ~28.3 MB
    else if (ws_size >= base + 1 * 8388608) nsplit = 2;   // ~12.7 MB
    const int steps = 128 / nsplit;

    k0_wt<<<512, 256, 0, stream>>>(weight, wt);
    k1_deg<<<8192, 256, 0, stream>>>(adj, dinv);
    k2_support<<<256, 512, 0, stream>>>(input, wt, dinv, sT);
    k3_spmm<<<dim3(128, nsplit), 512, 0, stream>>>(adj, sT, part, out, steps);
    k4_fin<<<2048, 256, 0, stream>>>(part, out, dinv, bias, nsplit);
}

// Round 6
// 136.895 us; speedup vs baseline: 1.0930x; 1.0930x over previous
//
#include <hip/hip_runtime.h>

// GraphConvolution: out = relu(D^-1/2 (2I - adj) D^-1/2 (input@weight) + b)
// N=8192, F_in=512, F_out=256. fp16 MFMA internally (needs 2^-12 rounding).
//
// R6: k3 keeps A-only LDS (R5) but B becomes COALESCED + DOUBLE-BUFFERED:
// sT stored in fragment-order 2KB chunks (lane l's B-fragment = bytes
// [l*16,l*16+16), kk=1 at +1024), so each wave's B load is contiguous-1KB
// dwordx4 pairs. One vmcnt(6) per step releases adj(kt+1)+B(kt); 6 vm ops
// stay in flight across every barrier (T4).

typedef _Float16 h4 __attribute__((ext_vector_type(4)));
typedef _Float16 h8 __attribute__((ext_vector_type(8)));
typedef float f4 __attribute__((ext_vector_type(4)));

__device__ __forceinline__ void gload_lds16(const void* g, void* l) {
    __builtin_amdgcn_global_load_lds(
        (const __attribute__((address_space(1))) void*)g,
        (__attribute__((address_space(3))) void*)l, 16, 0, 0);
}

// two 16B loads via inline asm: compiler cannot attach its own vmcnt(0)
__device__ __forceinline__ void gload2(const float* p, f4& x, f4& y) {
    asm volatile("global_load_dwordx4 %0, %2, off\n\t"
                 "global_load_dwordx4 %1, %2, off offset:16"
                 : "=&v"(x), "=&v"(y)
                 : "v"(p)
                 : "memory");
}
// B fragment pair from fragT chunk: kk=0 at +0, kk=1 at +1024 (coalesced 1KB)
__device__ __forceinline__ void gloadBfrag(const char* p, h8& x, h8& y) {
    asm volatile("global_load_dwordx4 %0, %2, off\n\t"
                 "global_load_dwordx4 %1, %2, off offset:1024"
                 : "=&v"(x), "=&v"(y)
                 : "v"(p)
                 : "memory");
}

// ---------------------------------------------------------------------------
// k0: weight [512][256] f32 -> W^T [256 j][512 k] fp16, XOR-swizzled within
// each 128B k-chunk: byte ^= ((j&7)<<4)  (consumed by k2's gload_lds path).
__global__ __launch_bounds__(256) void k0_wt(const float* __restrict__ weight,
                                             char* __restrict__ wt) {
    const int idx = blockIdx.x * 256 + threadIdx.x;   // 131072 total
    const int k = idx >> 8, j = idx & 255;
    const _Float16 h = (_Float16)weight[idx];
    const int off = j * 1024 + ((k >> 6) << 7) + (((k & 63) << 1) ^ ((j & 7) << 4));
    *(_Float16*)(wt + off) = h;
}

// ---------------------------------------------------------------------------
// k1: dinv[r] = 1/sqrt(2 + sum_k adj[r][k])
__global__ __launch_bounds__(256) void k1_deg(const float* __restrict__ adj,
                                              float* __restrict__ dinv) {
    const int r = blockIdx.x;
    const float4* rp = (const float4*)(adj + (size_t)r * 8192);
    const int t = threadIdx.x;
    float s = 0.f;
#pragma unroll
    for (int i = 0; i < 8; ++i) {
        float4 v = rp[t + i * 256];
        s += (v.x + v.y) + (v.z + v.w);
    }
#pragma unroll
    for (int off = 32; off > 0; off >>= 1) s += __shfl_down(s, off, 64);
    __shared__ float part[4];
    if ((t & 63) == 0) part[t >> 6] = s;
    __syncthreads();
    if (t == 0) {
        float deg = (part[0] + part[1]) + (part[2] + part[3]);
        dinv[r] = 1.0f / sqrtf(2.0f + deg);
    }
}

// ---------------------------------------------------------------------------
// fragT layout of S'^T (4 MB): for j in [0,256), k in [0,8192):
//   chunk = (j>>4)*128 + (k>>6)            (2048 B each)
//   off   = chunk*2048 + ((k>>5)&1)*1024 + (((k>>3)&3)*16 + (j&15))*16 + (k&7)*2
// Lane l of a wave reading chunk base + l*16 gets exactly its MFMA B-fragment
// (j = jb*16 + (l&15), k = kc*64 + kk*32 + (l>>4)*8 .. +8).
// ---------------------------------------------------------------------------
// k2: support = input @ weight; writes S' = dinv[k]*support[k][j] into fragT.
__global__ __launch_bounds__(512) void k2_support(const float* __restrict__ input,
                                                  const char* __restrict__ wt,
                                                  const float* __restrict__ dinv,
                                                  char* __restrict__ sT) {
    __shared__ char smem[4096 + 32768];   // A [32][128B] + B [256][128B]
    const int t = threadIdx.x, w = t >> 6, l = t & 63;
    const int r0 = (int)blockIdx.x * 32;
    const int arow = t >> 4, ak4 = t & 15;
    const int bj = l >> 3, bb = (l & 7) * 16;

    f4 acc[2][2] = {};

    for (int kt = 0; kt < 8; ++kt) {
        const int k0 = kt * 64;
        __syncthreads();
        // stage A: 32 rows x 64 k fp16, swizzled
        {
            float4 v = *(const float4*)(input + (size_t)(r0 + arow) * 512 + k0 + ak4 * 4);
            h4 h;
            h[0] = (_Float16)v.x; h[1] = (_Float16)v.y;
            h[2] = (_Float16)v.z; h[3] = (_Float16)v.w;
            *(h4*)(smem + arow * 128 + ((ak4 * 8) ^ ((arow & 7) << 4))) = h;
        }
        // stage B: W^T tile [256][64] fp16 via global_load_lds (pre-swizzled)
#pragma unroll
        for (int q = 0; q < 4; ++q) {
            const int c = q * 8 + w;
            gload_lds16(wt + (size_t)(c * 8 + bj) * 1024 + kt * 128 + bb,
                        smem + 4096 + c * 1024);
        }
        __syncthreads();
#pragma unroll
        for (int kk = 0; kk < 2; ++kk) {
            const int ko = kk * 64 + ((l >> 4) << 4);
            h8 a[2], b[2];
#pragma unroll
            for (int m = 0; m < 2; ++m) {
                const int r = m * 16 + (l & 15);
                a[m] = *(const h8*)(smem + r * 128 + (ko ^ ((r & 7) << 4)));
            }
#pragma unroll
            for (int n = 0; n < 2; ++n) {
                const int j = w * 32 + n * 16 + (l & 15);
                b[n] = *(const h8*)(smem + 4096 + j * 128 + (ko ^ ((j & 7) << 4)));
            }
#pragma unroll
            for (int m = 0; m < 2; ++m)
#pragma unroll
                for (int n = 0; n < 2; ++n)
                    acc[m][n] = __builtin_amdgcn_mfma_f32_16x16x32_f16(a[m], b[n], acc[m][n], 0, 0, 0);
        }
    }
    // epilogue -> fragT. C/D: col=l&15, row=(l>>4)*4+reg.
#pragma unroll
    for (int m = 0; m < 2; ++m)
#pragma unroll
        for (int n = 0; n < 2; ++n) {
            const int j = w * 32 + n * 16 + (l & 15);
            const int k0r = r0 + m * 16 + ((l >> 4) << 2);
            h4 h;
#pragma unroll
            for (int r = 0; r < 4; ++r)
                h[r] = (_Float16)(dinv[k0r + r] * acc[m][n][r]);
            const int off = (((j >> 4) * 128 + (k0r >> 6)) << 11) +
                            (((k0r >> 5) & 1) << 10) +
                            ((((k0r >> 3) & 3) << 4) + (j & 15)) * 16 +
                            ((k0r & 7) << 1);
            *(h4*)(sT + off) = h;
        }
}

// ---------------------------------------------------------------------------
// k3: partial[i][j] = sum_{k in split} (2I - adj)[i][k] * S'T[j][k]
// BM=64, BN=256, BK=64; 8 waves, wave tile 64Mx32N (B loaded once/block).
// 512 blocks (2/CU). A double-buffered in LDS (2x8KB); B double-buffered in
// regs via coalesced fragT loads. Counted vmcnt, one barrier/step.
__global__ __launch_bounds__(512, 4) void k3_spmm(const float* __restrict__ adj,
                                                  const char* __restrict__ sT,
                                                  float* __restrict__ part,
                                                  float* __restrict__ out,
                                                  int steps) {
    __shared__ __align__(16) char smem[2][8192];   // A tiles [64 rows][128 B]
    const int t = threadIdx.x;
    const int w = t >> 6, l = t & 63;
    const int i0 = (int)blockIdx.x * 64;
    const int ks0 = (int)blockIdx.y * steps * 64;
    const int dkt = (i0 - ks0) >> 6;   // uniform: K-step holding the diagonal

    const int arow = t >> 3;            // 0..63
    const int ak8 = (t & 7) * 8;        // 8 consecutive k per thread
    const int arow_g = i0 + arow;
    const float* aptr = adj + (size_t)arow_g * 8192 + ks0 + ak8;
    const int a_off = arow * 128 + (((t & 7) << 4) ^ ((arow & 7) << 4));

    // fragT pointers for this wave's two j-blocks (n=0,1)
    const int chunk0 = ks0 >> 6;
    const char* bpn0 = sT + ((size_t)(w * 2) * 128 + chunk0) * 2048 + l * 16;
    const char* bpn1 = bpn0 + 262144;   // +128 chunks

    f4 acc[4][2] = {};
    h8 bvA[2][2], bvB[2][2];            // [kk][n], ping-pong
    f4 ax0, ay0, ax1, ay1;              // adj ping-pong (depth-2)

    auto loadB = [&](int kt, h8 (&bv)[2][2]) {
        gloadBfrag(bpn0 + (size_t)kt * 2048, bv[0][0], bv[1][0]);
        gloadBfrag(bpn1 + (size_t)kt * 2048, bv[0][1], bv[1][1]);
    };
    auto writeA = [&](char* buf, int kt, const f4 x, const f4 y) {
        const int kg = ks0 + kt * 64 + ak8;
        h8 h;
        if (kt == dkt) {
#pragma unroll
            for (int e = 0; e < 4; ++e)
                h[e] = (_Float16)((arow_g == kg + e) ? 2.0f - x[e] : -x[e]);
#pragma unroll
            for (int e = 0; e < 4; ++e)
                h[4 + e] = (_Float16)((arow_g == kg + 4 + e) ? 2.0f - y[e] : -y[e]);
        } else {
#pragma unroll
            for (int e = 0; e < 4; ++e) h[e] = (_Float16)(-x[e]);
#pragma unroll
            for (int e = 0; e < 4; ++e) h[4 + e] = (_Float16)(-y[e]);
        }
        *(h8*)(buf + a_off) = h;
    };
    auto compute = [&](const char* A, const h8 (&bv)[2][2]) {
#pragma unroll
        for (int kk = 0; kk < 2; ++kk) {
            const int ko = kk * 64 + ((l >> 4) << 4);
            h8 a[4];
#pragma unroll
            for (int m = 0; m < 4; ++m) {
                const int r = m * 16 + (l & 15);
                a[m] = *(const h8*)(A + r * 128 + (ko ^ ((r & 7) << 4)));
            }
#pragma unroll
            for (int m = 0; m < 4; ++m)
#pragma unroll
                for (int n = 0; n < 2; ++n)
                    acc[m][n] = __builtin_amdgcn_mfma_f32_16x16x32_f16(a[m], bv[kk][n], acc[m][n], 0, 0, 0);
        }
    };

#define SBAR0() __builtin_amdgcn_sched_barrier(0)
#define WAIT_ADJ(N, X, Y)                                                     \
    asm volatile("s_waitcnt vmcnt(" #N ")" : "+v"(X), "+v"(Y) :: "memory");   \
    SBAR0();
#define WAIT_STEP(N, X, Y, BV)                                                \
    asm volatile("s_waitcnt vmcnt(" #N ")"                                    \
                 : "+v"(X), "+v"(Y), "+v"(BV[0][0]), "+v"(BV[0][1]),          \
                   "+v"(BV[1][0]), "+v"(BV[1][1]) :: "memory");               \
    SBAR0();
#define WAIT_BV(N, BV)                                                        \
    asm volatile("s_waitcnt vmcnt(" #N ")"                                    \
                 : "+v"(BV[0][0]), "+v"(BV[0][1]),                            \
                   "+v"(BV[1][0]), "+v"(BV[1][1]) :: "memory");               \
    SBAR0();
#define BARRIER()                                                             \
    asm volatile("s_waitcnt lgkmcnt(0)\n\ts_barrier" ::: "memory");           \
    SBAR0();

    // prologue: queue exits as [B(0) x4, adj(1) x2]; A(0) staged in LDS.
    gload2(aptr, ax0, ay0);             // 2
    loadB(0, bvA);                      // +4 = 6
    WAIT_ADJ(4, ax0, ay0)               // adj(0) ready, B(0) flying
    writeA(smem[0], 0, ax0, ay0);
    gload2(aptr + 64, ax1, ay1);        // +2 = 6
    BARRIER()

    // BODY(kt): issue B(kt+1)+adj(kt+2); vmcnt(6) releases adj(kt+1)+B(kt);
    // stage A(kt+1); compute(kt); barrier with 6 vm ops still in flight.
#define BODY(kt, XC, YC, XN, YN, BVC, BVN, BUFC, BUFN)                        \
    {                                                                         \
        loadB((kt) + 1, BVN);                                                 \
        gload2(aptr + (size_t)((kt) + 2) * 64, XC, YC);                       \
        WAIT_STEP(6, XN, YN, BVC)                                             \
        writeA(BUFN, (kt) + 1, XN, YN);                                       \
        compute(BUFC, BVC);                                                   \
        BARRIER()                                                             \
    }

    for (int kt2 = 0; kt2 + 2 <= steps - 2; kt2 += 2) {
        BODY(kt2,     ax0, ay0, ax1, ay1, bvA, bvB, smem[0], smem[1])
        BODY(kt2 + 1, ax1, ay1, ax0, ay0, bvB, bvA, smem[1], smem[0])
    }
    // peeled kt = steps-2 (even): load B(steps-1); no new adj
    {
        loadB(steps - 1, bvB);
        WAIT_STEP(4, ax1, ay1, bvA)
        writeA(smem[1], steps - 1, ax1, ay1);
        compute(smem[0], bvA);
        BARRIER()
    }
    // peeled kt = steps-1
    {
        WAIT_BV(0, bvB)
        compute(smem[1], bvB);
    }
#undef BODY
#undef WAIT_ADJ
#undef WAIT_STEP
#undef WAIT_BV
#undef BARRIER
#undef SBAR0

    // write f32 partial (last split writes into d_out)
    float* dst = (blockIdx.y == gridDim.y - 1) ? out
               : part + (size_t)blockIdx.y * (8192 * 256);
#pragma unroll
    for (int m = 0; m < 4; ++m)
#pragma unroll
        for (int n = 0; n < 2; ++n) {
            const int j = w * 32 + n * 16 + (l & 15);
            const int ib = i0 + m * 16 + ((l >> 4) << 2);
#pragma unroll
            for (int r = 0; r < 4; ++r)
                dst[(size_t)(ib + r) * 256 + j] = acc[m][n][r];
        }
}

// ---------------------------------------------------------------------------
// k4: out = relu(dinv[i] * (sum of partials) + b[j]); last partial is in out.
__global__ __launch_bounds__(256) void k4_fin(const float* __restrict__ part,
                                              float* __restrict__ out,
                                              const float* __restrict__ dinv,
                                              const float* __restrict__ bias,
                                              int nsplit) {
    const int idx = blockIdx.x * 256 + threadIdx.x;   // 524288 float4 groups
    float4 s = ((const float4*)out)[idx];
    for (int sp = 0; sp < nsplit - 1; ++sp)
        s += ((const float4*)(part + (size_t)sp * (8192 * 256)))[idx];
    const float dv = dinv[idx >> 6];
    const float4 b = ((const float4*)bias)[idx & 63];
    float4 r;
    r.x = fmaxf(dv * s.x + b.x, 0.f);
    r.y = fmaxf(dv * s.y + b.y, 0.f);
    r.z = fmaxf(dv * s.z + b.z, 0.f);
    r.w = fmaxf(dv * s.w + b.w, 0.f);
    ((float4*)out)[idx] = r;
}

// ---------------------------------------------------------------------------
extern "C" void kernel_launch(void* const* d_in, const int* in_sizes, int n_in,
                              void* d_out, int out_size, void* d_ws, size_t ws_size,
                              hipStream_t stream) {
    const float* input  = (const float*)d_in[0];   // [8192][512]
    const float* adj    = (const float*)d_in[1];   // [8192][8192]
    const float* weight = (const float*)d_in[2];   // [512][256]
    const float* bias   = (const float*)d_in[3];   // [256]
    float* out = (float*)d_out;                    // [8192][256]

    char* ws = (char*)d_ws;
    float* dinv = (float*)ws;                         // 32 KB
    char*  wt   = ws + 32768;                         // 256 KB
    char*  sT   = ws + 294912;                        // 4 MB (fp16, fragT)
    float* part = (float*)(ws + 294912 + 4194304);    // (nsplit-1) * 8 MB

    const size_t base = 294912 + 4194304;
    int nsplit = 1;
    if (ws_size >= base + 3 * 8388608) nsplit = 4;        // ~28.3 MB
    else if (ws_size >= base + 1 * 8388608) nsplit = 2;   // ~12.7 MB
    const int steps = 128 / nsplit;

    k0_wt<<<512, 256, 0, stream>>>(weight, wt);
    k1_deg<<<8192, 256, 0, stream>>>(adj, dinv);
    k2_support<<<256, 512, 0, stream>>>(input, wt, dinv, sT);
    k3_spmm<<<dim3(128, nsplit), 512, 0, stream>>>(adj, sT, part, out, steps);
    k4_fin<<<2048, 256, 0, stream>>>(part, out, dinv, bias, nsplit);
}